// Round 2
// baseline (159.739 us; speedup 1.0000x reference)
//
#include <hip/hip_runtime.h>

// out[b, i, j] = x[b, i + j];  B=128, L=8192, W=31, n_win = 8162.
// Row-partitioned streaming-write kernel:
//   grid.y = batch row b  -> no /PERB division, row base is SGPR-uniform
//   per row: PERB = 253022 floats (even, but !%4) -> float2 flat stream
//   one /31 per thread, K grid-steps with incremental (i,j) update
//   non-temporal stores: 129.5 MB stream should not thrash L2 (x stays resident)

constexpr int B_   = 128;
constexpr int L_   = 8192;
constexpr int W_   = 31;
constexpr int NWIN = L_ - (W_ - 1);          // 8162
constexpr int PERB = NWIN * W_;              // 253022 floats per batch row (even)
constexpr int N2   = PERB / 2;               // 126511 float2 per row
constexpr int BLOCK = 256;
constexpr int K     = 8;                     // float2 steps per thread
constexpr int BLOCKS_X = (N2 + BLOCK * K - 1) / (BLOCK * K);  // 62

typedef float f32x2 __attribute__((ext_vector_type(2)));   // native vec type: OK for nontemporal builtin

__global__ __launch_bounds__(BLOCK) void unfold_kernel(const float* __restrict__ x,
                                                       float* __restrict__ out) {
    const int b = blockIdx.y;
    const float* __restrict__ xb = x + b * L_;                       // SGPR base
    f32x2* __restrict__ ob = reinterpret_cast<f32x2*>(out) + (size_t)b * N2;

    unsigned t2 = blockIdx.x * (BLOCK * K) + threadIdx.x;            // float2 index in row
    unsigned q  = 2u * t2;                                           // element index in row
    unsigned i  = q / 31u;                                           // ONE magic-mul per thread
    unsigned j  = q - 31u * i;

#pragma unroll
    for (int s = 0; s < K; ++s) {
        if (t2 < (unsigned)N2) {
            unsigned in0 = i + j;                                    // x-offset of elem q
            // elem q+1: j+1 (same i) unless j==30 -> (i+1, 0): in0+1-30
            unsigned in1 = in0 + 1u - (j == 30u ? 30u : 0u);
            f32x2 v;
            v.x = xb[in0];
            v.y = xb[in1];
            __builtin_nontemporal_store(v, &ob[t2]);
        }
        // advance one grid-step: +BLOCK float2 = +512 elements = 16*31 + 16
        t2 += BLOCK;
        i  += 16u;
        j  += 16u;
        if (j >= 31u) { j -= 31u; ++i; }                             // single carry (j<=46)
    }
}

extern "C" void kernel_launch(void* const* d_in, const int* in_sizes, int n_in,
                              void* d_out, int out_size, void* d_ws, size_t ws_size,
                              hipStream_t stream) {
    const float* x = (const float*)d_in[0];
    float* out = (float*)d_out;
    dim3 grid(BLOCKS_X, B_);
    unfold_kernel<<<grid, BLOCK, 0, stream>>>(x, out);
}

// Round 4
// 146.444 us; speedup vs baseline: 1.0908x; 1.0908x over previous
//
#include <hip/hip_runtime.h>

// out[b, i, j] = x[b, i + j];  B=128, L=8192, W=31, n_win = 8162.
// Flat float4 output stream (16B-aligned, matches the 6.35 TB/s fill kernel's
// store pattern; NO nontemporal). Cheap index math: 2 divisions per thread,
// then K grid-steps with incremental (i,j) update.

constexpr int B_   = 128;
constexpr int L_   = 8192;
constexpr int W_   = 31;
constexpr int NWIN = L_ - (W_ - 1);               // 8162
constexpr int PERB = NWIN * W_;                   // 253022 floats per batch row
constexpr long long TOTAL = (long long)B_ * PERB; // 32,386,816 (div by 4)
constexpr int NVEC  = (int)(TOTAL / 4);           // 8,096,704 float4 stores
constexpr int BLOCK = 256;
constexpr int K     = 4;                          // float4s per thread
constexpr int CHUNK = BLOCK * K;                  // 1024 float4 per block
constexpr int GRID  = (NVEC + CHUNK - 1) / CHUNK; // 7907 (tail guarded)

typedef float f32x4 __attribute__((ext_vector_type(4)));

__global__ __launch_bounds__(BLOCK) void unfold_kernel(const float* __restrict__ x,
                                                       float* __restrict__ out) {
    unsigned t = blockIdx.x * CHUNK + threadIdx.x;   // float4 index in flat stream
    unsigned o = t << 2;                             // flat element index
    unsigned b = o / (unsigned)PERB;                 // magic-mul, once
    unsigned q = o - b * (unsigned)PERB;             // element index within row
    unsigned i = q / 31u;                            // magic-mul, once
    unsigned j = q - 31u * i;
    const float* __restrict__ xb = x + b * L_;       // per-lane row base
    f32x4* __restrict__ o4 = reinterpret_cast<f32x4*>(out);

#pragma unroll
    for (int s = 0; s < K; ++s) {
        if (t < (unsigned)NVEC) {
            f32x4 v;
            unsigned base = i + j;                   // x-offset of element q
#pragma unroll
            for (int k = 0; k < 4; ++k) {
                unsigned jk  = j + (unsigned)k;
                unsigned idx = base + (unsigned)k - (jk >= 31u ? 30u : 0u);
                float val;
                if (q + (unsigned)k >= (unsigned)PERB) {
                    // group straddles a batch-row boundary (127 of these total):
                    // element belongs to row b+1, i=0, j = q+k-PERB (< 4)
                    val = xb[L_ + (q + (unsigned)k - (unsigned)PERB)];
                } else {
                    val = xb[idx];
                }
                v[k] = val;
            }
            o4[t] = v;
        }
        // advance one grid-step: +BLOCK float4 = +1024 elements = 33*31 + 1
        t += BLOCK;
        q += 1024u;
        i += 33u;
        j += 1u;
        if (j >= 31u) { j -= 31u; ++i; }
        if (q >= (unsigned)PERB) {                   // crossed into next batch row
            q -= (unsigned)PERB;                     // q < 1024 now
            xb += L_;
            i = q / 31u;                             // rare, cheap magic-mul
            j = q - 31u * i;
        }
    }
}

extern "C" void kernel_launch(void* const* d_in, const int* in_sizes, int n_in,
                              void* d_out, int out_size, void* d_ws, size_t ws_size,
                              hipStream_t stream) {
    const float* x = (const float*)d_in[0];
    float* out = (float*)d_out;
    unfold_kernel<<<GRID, BLOCK, 0, stream>>>(x, out);
}

// Round 5
// 136.161 us; speedup vs baseline: 1.1732x; 1.0755x over previous
//
#include <hip/hip_runtime.h>

// out[b, i, j] = x[b, i + j];  B=128, L=8192, W=31, n_win = 8162.
// Flat float4 output stream. Each float4 covers output cols j..j+3 of window i
// (possibly wrapping into window i+1). Key identity: wrapped elements are the
// head of x[i+1..], so every group is an element-select between TWO dwordx4
// loads:  A = x[i+j .. i+j+3],  B = x[i+1 .. i+4].  VMEM: 5 -> 3 instrs/float4,
// no per-element divergence. Rare paths (row straddle, b=127 buffer end) are
// exec-masked and branched over by ~99.8% of waves.

constexpr int B_   = 128;
constexpr int L_   = 8192;
constexpr int W_   = 31;
constexpr int NWIN = L_ - (W_ - 1);               // 8162
constexpr int PERB = NWIN * W_;                   // 253022 floats per batch row
constexpr long long TOTAL = (long long)B_ * PERB; // 32,386,816 (div by 4)
constexpr int NVEC  = (int)(TOTAL / 4);           // 8,096,704 float4 stores
constexpr int BLOCK = 256;
constexpr int K     = 4;                          // float4s per thread
constexpr int CHUNK = BLOCK * K;                  // 1024 float4 per block
constexpr int GRID  = (NVEC + CHUNK - 1) / CHUNK; // 7907

typedef float f32x4  __attribute__((ext_vector_type(4)));
typedef float f32x4u __attribute__((ext_vector_type(4), aligned(4)));  // 4B-aligned wide load

__global__ __launch_bounds__(BLOCK) void unfold_kernel(const float* __restrict__ x,
                                                       float* __restrict__ out) {
    unsigned t = blockIdx.x * CHUNK + threadIdx.x;   // float4 index in flat stream
    unsigned o = t << 2;                             // flat element index
    unsigned b = o / (unsigned)PERB;                 // magic-mul, once
    unsigned q = o - b * (unsigned)PERB;             // element index within row
    unsigned i = q / 31u;                            // magic-mul, once
    unsigned j = q - 31u * i;
    const float* __restrict__ xb = x + b * L_;
    f32x4* __restrict__ o4 = reinterpret_cast<f32x4*>(out);

#pragma unroll
    for (int s = 0; s < K; ++s) {
        if (t < (unsigned)NVEC) {
            unsigned base = i + j;
            // rare: group straddles batch row (127 total), or A-load would read
            // past the end of the whole x buffer (b==127, last ~3 groups' span).
            bool rare = (q + 3u >= (unsigned)PERB) ||
                        (b == (unsigned)(B_ - 1) && base + 3u >= (unsigned)L_);
            f32x4 v;
            if (!rare) {
                f32x4 A  = *reinterpret_cast<const f32x4u*>(xb + base);     // x[i+j ..]
                f32x4 Bv = *reinterpret_cast<const f32x4u*>(xb + i + 1u);   // x[i+1 ..]
                v.x = A.x;                                                  // j+0 < 31 always
                v.y = (j < 30u) ? A.y : Bv.x;
                v.z = (j < 29u) ? A.z : ((j == 29u) ? Bv.x : Bv.y);
                v.w = (j < 28u) ? A.w : ((j == 28u) ? Bv.x
                                     : ((j == 29u) ? Bv.y : Bv.z));
            } else {
                float vv[4];
#pragma unroll
                for (int k = 0; k < 4; ++k) {
                    unsigned qk = q + (unsigned)k;
                    float val;
                    if (qk >= (unsigned)PERB) {
                        // belongs to next batch row, i=0, j = qk-PERB (< 4)
                        val = xb[L_ + (qk - (unsigned)PERB)];
                    } else {
                        unsigned jk  = j + (unsigned)k;
                        unsigned idx = base + (unsigned)k - (jk >= 31u ? 30u : 0u);
                        val = xb[idx];
                    }
                    vv[k] = val;
                }
                v.x = vv[0]; v.y = vv[1]; v.z = vv[2]; v.w = vv[3];
            }
            o4[t] = v;
        }
        // advance one grid-step: +BLOCK float4 = +1024 elements = 33*31 + 1
        t += BLOCK;
        q += 1024u;
        i += 33u;
        j += 1u;
        if (j >= 31u) { j -= 31u; ++i; }
        if (q >= (unsigned)PERB) {                   // crossed into next batch row
            q -= (unsigned)PERB;
            xb += L_;
            ++b;
            i = q / 31u;                             // rare, cheap magic-mul
            j = q - 31u * i;
        }
    }
}

extern "C" void kernel_launch(void* const* d_in, const int* in_sizes, int n_in,
                              void* d_out, int out_size, void* d_ws, size_t ws_size,
                              hipStream_t stream) {
    const float* x = (const float*)d_in[0];
    float* out = (float*)d_out;
    unfold_kernel<<<GRID, BLOCK, 0, stream>>>(x, out);
}

// Round 6
// 131.852 us; speedup vs baseline: 1.2115x; 1.0327x over previous
//
#include <hip/hip_runtime.h>

// out[b, i, j] = x[b, i + j];  B=128, L=8192, W=31, n_win = 8162.
// LDS-staged version: a block producing 4096 output elements only touches
// ~660 B of x (31x expansion). Stage that span in LDS once, serve all window
// gathers with ds_read_b32 (lgkm pipe, overlaps the store drain), and keep
// the store as the fill-kernel-proven flat dwordx4 stream. VMEM per float4:
// 3 -> 1. Row-straddle blocks (127/7907) stage a second span from row b+1.

constexpr int B_   = 128;
constexpr int L_   = 8192;
constexpr int W_   = 31;
constexpr int NWIN = L_ - (W_ - 1);               // 8162
constexpr int PERB = NWIN * W_;                   // 253022 floats per batch row
constexpr long long TOTAL = (long long)B_ * PERB; // 32,386,816 (div by 4)
constexpr int NVEC  = (int)(TOTAL / 4);           // 8,096,704 float4 stores
constexpr int BLOCK = 256;
constexpr int K     = 4;                          // float4s per thread
constexpr int CHUNK = BLOCK * K;                  // 1024 float4 = 4096 elements
constexpr int GRID  = (NVEC + CHUNK - 1) / CHUNK; // 7907
constexpr int ELEMS = CHUNK * 4;                  // 4096 elements per block
constexpr int SPAN  = 168;                        // LDS span per row (max needed 164)

typedef float f32x4 __attribute__((ext_vector_type(4)));

__global__ __launch_bounds__(BLOCK) void unfold_kernel(const float* __restrict__ x,
                                                       float* __restrict__ out) {
    __shared__ float lds[2 * SPAN];

    const unsigned o0 = blockIdx.x * (unsigned)ELEMS;       // first flat element
    const unsigned b  = o0 / (unsigned)PERB;                // magic-mul
    const unsigned q0 = o0 - b * (unsigned)PERB;            // within-row start
    const unsigned qL = (q0 + (unsigned)ELEMS - 1u < (unsigned)PERB - 1u)
                        ? (q0 + (unsigned)ELEMS - 1u) : ((unsigned)PERB - 1u);
    const unsigned i_lo = q0 / 31u;
    const unsigned i_hi = qL / 31u;
    const unsigned n0   = i_hi - i_lo + 31u;                // <= 164

    const float* __restrict__ xb = x + b * L_;
    for (unsigned k = threadIdx.x; k < n0; k += BLOCK)      // one pass: n0 < 256
        lds[k] = xb[i_lo + k];

    const bool straddle = (q0 + (unsigned)ELEMS > (unsigned)PERB) &&
                          (b + 1u < (unsigned)B_);
    if (straddle) {
        unsigned q1max = q0 + (unsigned)ELEMS - 1u - (unsigned)PERB; // <= 4094
        unsigned n1 = q1max / 31u + 31u;                    // <= 163
        const float* __restrict__ xb1 = xb + L_;
        for (unsigned k = threadIdx.x; k < n1; k += BLOCK)
            lds[SPAN + k] = xb1[k];
    }
    __syncthreads();

    unsigned t = blockIdx.x * CHUNK + threadIdx.x;          // float4 index
    unsigned q = q0 + 4u * threadIdx.x;                     // within-row element coord
    unsigned boff = 0, ibase = i_lo;
    bool sel1 = false;
    if (q >= (unsigned)PERB) {                              // thread starts in row b+1
        q -= (unsigned)PERB; sel1 = true; boff = SPAN; ibase = 0;
    }
    unsigned i = q / 31u;                                   // magic-mul, once
    unsigned j = q - 31u * i;
    f32x4* __restrict__ o4 = reinterpret_cast<f32x4*>(out);

#pragma unroll
    for (int s = 0; s < K; ++s) {
        if (t < (unsigned)NVEC) {
            f32x4 v;
            unsigned idx0 = boff + (i + j - ibase);         // lds idx of elem q
#pragma unroll
            for (int k = 0; k < 4; ++k) {
                unsigned jk  = j + (unsigned)k;
                unsigned idx = idx0 + (unsigned)k - (jk >= 31u ? 30u : 0u);
                if (!sel1 && q + (unsigned)k >= (unsigned)PERB)      // elem in row b+1
                    idx = (unsigned)SPAN + (q + (unsigned)k - (unsigned)PERB);
                v[k] = lds[idx];
            }
            o4[t] = v;
        }
        // advance one grid-step: +BLOCK float4 = +1024 elements = 33*31 + 1
        t += BLOCK;
        q += 1024u;
        if (!sel1 && q >= (unsigned)PERB) {                 // crossed into row b+1
            q -= (unsigned)PERB;                            // q < 1024 now
            sel1 = true; boff = SPAN; ibase = 0;
            i = q / 31u;                                    // rare magic-mul
            j = q - 31u * i;
        } else {
            i += 33u; j += 1u;
            if (j >= 31u) { j -= 31u; ++i; }                // single carry
        }
    }
}

extern "C" void kernel_launch(void* const* d_in, const int* in_sizes, int n_in,
                              void* d_out, int out_size, void* d_ws, size_t ws_size,
                              hipStream_t stream) {
    const float* x = (const float*)d_in[0];
    float* out = (float*)d_out;
    unfold_kernel<<<GRID, BLOCK, 0, stream>>>(x, out);
}